// Round 1
// baseline (25.570 us; speedup 1.0000x reference)
//
#include <hip/hip_runtime.h>

// Reference collapses: softmax over a singleton axis == 1.0 exactly, so
// a = attn(Q,K)+attn(Q,T)+attn(T,K) = 3.0 everywhere and out = 3.0 * x.
// Pure memory-bound elementwise scale: 64 MiB in + 64 MiB out.

__global__ void __launch_bounds__(256) esra_scale3_kernel(
    const float4* __restrict__ x, float4* __restrict__ out, int n4) {
    int stride = gridDim.x * blockDim.x;
    for (int i = blockIdx.x * blockDim.x + threadIdx.x; i < n4; i += stride) {
        float4 v = x[i];
        v.x *= 3.0f;
        v.y *= 3.0f;
        v.z *= 3.0f;
        v.w *= 3.0f;
        out[i] = v;
    }
}

extern "C" void kernel_launch(void* const* d_in, const int* in_sizes, int n_in,
                              void* d_out, int out_size, void* d_ws, size_t ws_size,
                              hipStream_t stream) {
    const float4* x = (const float4*)d_in[0];   // [B,C,H,W] fp32, 16*256*64*64
    float4* out = (float4*)d_out;               // same shape, fp32
    int n4 = out_size / 4;                      // 16777216 / 4 = 4194304, divisible
    const int block = 256;
    const int grid = 2048;                      // 256 CUs * 8 blocks, grid-stride
    esra_scale3_kernel<<<grid, block, 0, stream>>>(x, out, n4);
}